// Round 18
// baseline (313.150 us; speedup 1.0000x reference)
//
#include <hip/hip_runtime.h>
#include <hip/hip_bf16.h>

// Sparse MoE v18: B operands read DIRECTLY from L2 into registers (blocked
// layout makes wave fragments contiguous) -- LDS traffic halved (the measured
// ~120us gateup plateau was LDS-pipe-bound: 48KB/step -> 24KB/step). A stays
// LDS-staged (gathered). 2-set B reg ping-pong + 2-buffer A, vmcnt(6).
// Fused cvt+router (no global atomics), prefix_place, combine from R17.
// T=4096 tokens, D=2048, E=8, F_E=1024, top-2, SCALE=4.

#define TOK 4096
#define DIM 2048
#define NE 8
#define FE 1024
#define SCALE_F 4.0f
#define BK 32

typedef __bf16 bf16x8 __attribute__((ext_vector_type(8)));
typedef __bf16 bf16x4 __attribute__((ext_vector_type(4)));
typedef float f32x4 __attribute__((ext_vector_type(4)));

__device__ __forceinline__ void gll16(const void* g, void* l) {
  __builtin_amdgcn_global_load_lds(
      (const __attribute__((address_space(1))) unsigned int*)g,
      (__attribute__((address_space(3))) unsigned int*)l, 16, 0, 0);
}

#define MFMA16(a, b, c) __builtin_amdgcn_mfma_f32_16x16x32_bf16((a), (b), (c), 0, 0, 0)
#define VMCNT6 asm volatile("s_waitcnt vmcnt(6)" ::: "memory")
#define VMCNT0 asm volatile("s_waitcnt vmcnt(0)" ::: "memory")
#define LGKM0  asm volatile("s_waitcnt lgkmcnt(0)" ::: "memory")
#define SCHED0 __builtin_amdgcn_sched_barrier(0)
#define BAR    __builtin_amdgcn_s_barrier()

// ---- fused: blocks [0,TOK) = router (no global atomics); [TOK,+3072) = cvt --
__global__ __launch_bounds__(256) void k_fused_cvt_router(
    const float* __restrict__ x, const float* __restrict__ rw,
    const float* __restrict__ nwt, __bf16* __restrict__ xbf,
    int* __restrict__ topi, float* __restrict__ topw,
    const float* __restrict__ gw, const float* __restrict__ uw,
    const float* __restrict__ dwp, __bf16* __restrict__ gwt,
    __bf16* __restrict__ uwt, __bf16* __restrict__ dwt) {
  __shared__ __align__(16) __bf16 lt[128][136];   // 34 KB
  int tid = threadIdx.x;

  if (blockIdx.x < TOK) {
    int t = blockIdx.x;
    const float* xr = x + (size_t)t * DIM;
    float ssq = 0.f;
    float pe[NE];
#pragma unroll
    for (int e = 0; e < NE; ++e) pe[e] = 0.f;

#pragma unroll
    for (int i = 0; i < 2; ++i) {
      int c4 = tid + i * 256;
      float4 v = ((const float4*)xr)[c4];
      int c = c4 * 4;
      bf16x4 b;
      b[0] = (__bf16)v.x; b[1] = (__bf16)v.y; b[2] = (__bf16)v.z; b[3] = (__bf16)v.w;
      *(bf16x4*)(xbf + (size_t)t * DIM + c) = b;
      float m0 = nwt[c + 0] * v.x, m1 = nwt[c + 1] * v.y;
      float m2 = nwt[c + 2] * v.z, m3 = nwt[c + 3] * v.w;
      ssq += v.x * v.x + v.y * v.y + v.z * v.z + v.w * v.w;
#pragma unroll
      for (int e = 0; e < NE; ++e) {
        float4 rv = ((const float4*)(rw + (size_t)e * DIM))[c4];
        pe[e] += m0 * rv.x + m1 * rv.y + m2 * rv.z + m3 * rv.w;
      }
    }
#pragma unroll
    for (int off = 32; off > 0; off >>= 1) {
      ssq += __shfl_down(ssq, off);
#pragma unroll
      for (int e = 0; e < NE; ++e) pe[e] += __shfl_down(pe[e], off);
    }
    float (*red)[NE + 1] = (float (*)[NE + 1])&lt[0][0];
    int wid = tid >> 6, lane = tid & 63;
    if (lane == 0) {
      red[wid][0] = ssq;
#pragma unroll
      for (int e = 0; e < NE; ++e) red[wid][1 + e] = pe[e];
    }
    __syncthreads();
    if (tid == 0) {
      float s = red[0][0] + red[1][0] + red[2][0] + red[3][0];
      float rs = rsqrtf(s / (float)DIM + 1e-6f);
      float l[NE];
#pragma unroll
      for (int e = 0; e < NE; ++e)
        l[e] = (red[0][1 + e] + red[1][1 + e] + red[2][1 + e] + red[3][1 + e]) * rs;
      int i1 = 0;
#pragma unroll
      for (int e = 1; e < NE; ++e) if (l[e] > l[i1]) i1 = e;
      int i2 = -1;
#pragma unroll
      for (int e = 0; e < NE; ++e) if (e != i1 && (i2 < 0 || l[e] > l[i2])) i2 = e;
      float e2 = __expf(l[i2] - l[i1]);
      float inv = 1.f / (1.f + e2);
      topi[2 * t] = i1; topi[2 * t + 1] = i2;
      topw[2 * t] = inv; topw[2 * t + 1] = e2 * inv;
    }
  } else {
    // convert: [K][N] f32 -> blocked bf16 ([64n][32k] blocks, 4KB streaming)
    int bx = blockIdx.x - TOK;
    int m = bx >> 7;
    int tilex = bx & 127;
    int which = m >> 3, e = m & 7;
    const float* src; __bf16* dst; int K, N;
    if (which == 0)      { src = gw;  dst = gwt; K = DIM; N = FE; }
    else if (which == 1) { src = uw;  dst = uwt; K = DIM; N = FE; }
    else                 { src = dwp; dst = dwt; K = FE;  N = DIM; }
    src += (size_t)e * K * N;
    dst += (size_t)e * K * N;
    int tiles_n = N / 128;
    int k0 = (tilex / tiles_n) * 128, n0c = (tilex % tiles_n) * 128;

#pragma unroll
    for (int p = 0; p < 16; ++p) {
      int idx = tid + p * 256;
      int row = idx >> 5, c4 = idx & 31;
      float4 v = *(const float4*)(src + (size_t)(k0 + row) * N + n0c + c4 * 4);
      int cc = c4 * 4;
      lt[cc + 0][row] = (__bf16)v.x;
      lt[cc + 1][row] = (__bf16)v.y;
      lt[cc + 2][row] = (__bf16)v.z;
      lt[cc + 3][row] = (__bf16)v.w;
    }
    __syncthreads();
    int kblocks = K >> 5;
    int n_ = tid >> 2, kc = tid & 3;
#pragma unroll
    for (int q = 0; q < 8; ++q) {
      int bn = q >> 2, bk = q & 3;
      size_t blk = ((size_t)((n0c >> 6) + bn) * kblocks + (k0 >> 5) + bk) * 2048;
      bf16x8 w = *(const bf16x8*)&lt[bn * 64 + n_][bk * 32 + kc * 8];
      *(bf16x8*)(dst + blk + n_ * 32 + kc * 8) = w;
    }
  }
}

// ---- prefix + place with LDS histogram --------------------------------------
__global__ __launch_bounds__(256) void k_prefix_place(
    int* __restrict__ offsets, const int* __restrict__ topi,
    const float* __restrict__ topw, int* __restrict__ row_token,
    float* __restrict__ row_wt, int* __restrict__ invp) {
  __shared__ int hist[4][NE];
  __shared__ int lcur[NE];
  int tid = threadIdx.x, wid = tid >> 6;
  if (tid < 4 * NE) ((int*)hist)[tid] = 0;
  __syncthreads();
  for (int i = tid; i < 2 * TOK; i += 256)
    atomicAdd(&hist[wid][topi[i]], 1);
  __syncthreads();
  if (tid == 0) {
    int acc = 0;
    for (int e = 0; e < NE; ++e) {
      int c = hist[0][e] + hist[1][e] + hist[2][e] + hist[3][e];
      offsets[e] = acc;
      lcur[e] = acc;
      acc += c;
    }
    offsets[NE] = acc;
  }
  __syncthreads();
  for (int t = tid; t < TOK; t += 256) {
#pragma unroll
    for (int s = 0; s < 2; ++s) {
      int e = topi[2 * t + s];
      int pos = atomicAdd(&lcur[e], 1);
      row_token[pos] = t;
      row_wt[pos] = topw[2 * t + s] * SCALE_F;
      invp[2 * t + s] = pos;
    }
  }
}

// ---- combine ----------------------------------------------------------------
__global__ __launch_bounds__(256) void k_combine(
    const __bf16* __restrict__ dbuf, const float* __restrict__ topw,
    const int* __restrict__ invp, float* __restrict__ out) {
  int t = blockIdx.x;
  int c = threadIdx.x * 8;
  int p0 = invp[2 * t], p1 = invp[2 * t + 1];
  float w0 = topw[2 * t] * SCALE_F, w1 = topw[2 * t + 1] * SCALE_F;
  bf16x8 a = *(const bf16x8*)(dbuf + (size_t)p0 * DIM + c);
  bf16x8 b = *(const bf16x8*)(dbuf + (size_t)p1 * DIM + c);
  float4 o0, o1;
  o0.x = w0 * (float)a[0] + w1 * (float)b[0];
  o0.y = w0 * (float)a[1] + w1 * (float)b[1];
  o0.z = w0 * (float)a[2] + w1 * (float)b[2];
  o0.w = w0 * (float)a[3] + w1 * (float)b[3];
  o1.x = w0 * (float)a[4] + w1 * (float)b[4];
  o1.y = w0 * (float)a[5] + w1 * (float)b[5];
  o1.z = w0 * (float)a[6] + w1 * (float)b[6];
  o1.w = w0 * (float)a[7] + w1 * (float)b[7];
  *(float4*)(out + (size_t)t * DIM + c) = o0;
  *(float4*)(out + (size_t)t * DIM + c + 4) = o1;
}

// ================= FAST PATH: B-in-registers GEMMs ===========================
// XCD remap: nw=(lin&7)*512+(lin>>3); y=nw&31, x=(nw>>5)&15, e=nw>>9.
// A swizzle (LDS): stage src chunk ((lane&3)^((lane>>3)&3))*8,
// read chunk ((lane>>4)^((lane>>1)&3))*8. B: direct global, natural chunk.

// gate/up fused GEMM + SiLU, 128x64 tile. A in LDS (2-buf), B in regs (2-set).
// grid: 4096 linear.
__global__ __launch_bounds__(256) void k_gateup18(
    const __bf16* __restrict__ xbf, const __bf16* __restrict__ gwt,
    const __bf16* __restrict__ uwt, const int* __restrict__ row_token,
    const int* __restrict__ offsets, __bf16* __restrict__ abuf) {
  int lin = blockIdx.x;
  int nw = (lin & 7) * 512 + (lin >> 3);
  int ytile = nw & 31, xt = (nw >> 5) & 15, e = nw >> 9;
  int row_start = offsets[e], row_end = offsets[e + 1];
  int tile_row = row_start + ytile * 128;
  if (tile_row >= row_end) return;
  int n0 = xt * 64;

  __shared__ __align__(16) __bf16 As0[128][BK], As1[128][BK];
  __shared__ int toks[128];

  int tid = threadIdx.x;
  if (tid < 128) {
    int r = tile_row + tid;
    toks[tid] = (r < row_end) ? row_token[r] : row_token[row_start];
  }
  __syncthreads();

  int wid = tid >> 6, lane = tid & 63;
  int lrow = lane >> 2;
  int lke = (((lane & 3) ^ ((lane >> 3) & 3)) * 8);
  int lks = (((lane >> 4) ^ ((lane >> 1) & 3)) * 8);

  const __bf16* pa0 = xbf + (size_t)toks[wid * 32 + lrow] * DIM + lke;
  const __bf16* pa1 = xbf + (size_t)toks[wid * 32 + 16 + lrow] * DIM + lke;

  int lr = lane & 15;
  int wm = (wid >> 1) * 64, wn = (wid & 1) * 32;
  int chunk = (lane >> 4) * 8;   // natural chunk for direct B reads

  // B frag pointers (blocked layout): frag ni at +ni*512; +2048 per K-step.
  const __bf16* pgB = gwt + (size_t)e * FE * DIM + (size_t)xt * 64 * 2048 +
                      (wn + lr) * 32 + chunk;
  const __bf16* puB = uwt + (size_t)e * FE * DIM + (size_t)xt * 64 * 2048 +
                      (wn + lr) * 32 + chunk;

  f32x4 accg[4][2], accu[4][2];
#pragma unroll
  for (int i = 0; i < 4; ++i)
#pragma unroll
    for (int j = 0; j < 2; ++j) { accg[i][j] = (f32x4)0.f; accu[i][j] = (f32x4)0.f; }

  bf16x8 af0, af1, af2, af3;
  bf16x8 eg0, eg1, eu0, eu1;   // even-step B regs
  bf16x8 og0, og1, ou0, ou1;   // odd-step B regs

#define GU_STAGE_A(AS)                                       \
  do {                                                       \
    gll16(pa0, (void*)&AS[wid * 32][0]);                     \
    gll16(pa1, (void*)&AS[wid * 32 + 16][0]);                \
    pa0 += BK; pa1 += BK;                                    \
  } while (0)

#define GU_LOAD_B(G0, G1, U0, U1)                            \
  do {                                                       \
    G0 = *(const bf16x8*)pgB;                                \
    G1 = *(const bf16x8*)(pgB + 512);                        \
    U0 = *(const bf16x8*)puB;                                \
    U1 = *(const bf16x8*)(puB + 512);                        \
    pgB += 2048; puB += 2048;                                \
  } while (0)

#define GU_LOAD_A(AS)                                        \
  do {                                                       \
    af0 = *(const bf16x8*)&AS[wm + lr][lks];                 \
    af1 = *(const bf16x8*)&AS[wm + 16 + lr][lks];            \
    af2 = *(const bf16x8*)&AS[wm + 32 + lr][lks];            \
    af3 = *(const bf16x8*)&AS[wm + 48 + lr][lks];            \
  } while (0)

#define GU_MFMA(G0, G1, U0, U1)                              \
  do {                                                       \
    __builtin_amdgcn_s_setprio(1);                           \
    accg[0][0] = MFMA16(af0, G0, accg[0][0]);                \
    accg[0][1] = MFMA16(af0, G1, accg[0][1]);                \
    accu[0][0] = MFMA16(af0, U0, accu[0][0]);                \
    accu[0][1] = MFMA16(af0, U1, accu[0][1]);                \
    accg[1][0] = MFMA16(af1, G0, accg[1][0]);                \
    accg[1][1] = MFMA16(af1, G1, accg[1][1]);                \
    accu[1][0] = MFMA16(af1, U0, accu[1][0]);                \
    accu[1][1] = MFMA16(af1, U1, accu[1][1]);                \
    accg[2][0] = MFMA16(af2, G0, accg[2][0]);                \
    accg[2][1] = MFMA16(af2, G1, accg[2][1]);                \
    accu[2][0] = MFMA16(af2, U0, accu[2][0]);                \
    accu[2][1] = MFMA16(af2, U1, accu[2][1]);                \
    accg[3][0] = MFMA16(af3, G0, accg[3][0]);                \
    accg[3][1] = MFMA16(af3, G1, accg[3][1]);                \
    accu[3][0] = MFMA16(af3, U0, accu[3][0]);                \
    accu[3][1] = MFMA16(af3, U1, accu[3][1]);                \
    __builtin_amdgcn_s_setprio(0);                           \
  } while (0)

  // prologue: tiles 0,1 in flight. Queue: [A0:2, B0:4, A1:2, B1:4]
  GU_STAGE_A(As0);
  GU_LOAD_B(eg0, eg1, eu0, eu1);
  GU_STAGE_A(As1);
  GU_LOAD_B(og0, og1, ou0, ou1);
  // main: t = 0..61 (31 pairs). Steady vmcnt(6) = wait oldest {A(t),B(t)}.
#pragma unroll 1
  for (int it = 0; it < 31; ++it) {
    VMCNT6; BAR;
    GU_LOAD_A(As0);
    LGKM0; SCHED0; BAR;
    GU_STAGE_A(As0);
    GU_MFMA(eg0, eg1, eu0, eu1);
    GU_LOAD_B(eg0, eg1, eu0, eu1);
    VMCNT6; BAR;
    GU_LOAD_A(As1);
    LGKM0; SCHED0; BAR;
    GU_STAGE_A(As1);
    GU_MFMA(og0, og1, ou0, ou1);
    GU_LOAD_B(og0, og1, ou0, ou1);
  }
  // t=62 (As0, even set): 12 outstanding -> wait own 6
  VMCNT6; BAR;
  GU_LOAD_A(As0);
  LGKM0; SCHED0;
  GU_MFMA(eg0, eg1, eu0, eu1);
  // t=63 (As1, odd set): drain
  VMCNT0; BAR;
  GU_LOAD_A(As1);
  LGKM0; SCHED0;
  GU_MFMA(og0, og1, ou0, ou1);
#undef GU_STAGE_A
#undef GU_LOAD_B
#undef GU_LOAD_A
#undef GU_MFMA

  int rowq = (lane >> 4) * 4;
  f32x4* ag = &accg[0][0];
  f32x4* au = &accu[0][0];
#pragma unroll
  for (int mi = 0; mi < 4; ++mi) {
#pragma unroll
    for (int ni = 0; ni < 2; ++ni) {
#pragma unroll
      for (int j = 0; j < 4; ++j) {
        int rg = tile_row + wm + mi * 16 + rowq + j;
        if (rg < row_end) {
          float g = ag[mi * 2 + ni][j], u = au[mi * 2 + ni][j];
          float sig = 1.f / (1.f + __expf(-g));
          abuf[(size_t)rg * FE + n0 + wn + ni * 16 + lr] = (__bf16)(g * sig * u);
        }
      }
    }
  }
}

// down GEMM -> dbuf. 128x128 tile. A in LDS (2-buf), B in regs (2-set).
// grid: 4096 linear.
__global__ __launch_bounds__(256) void k_down18(
    const __bf16* __restrict__ abuf, const __bf16* __restrict__ dwt,
    const int* __restrict__ offsets, __bf16* __restrict__ dbuf) {
  int lin = blockIdx.x;
  int nw = (lin & 7) * 512 + (lin >> 3);
  int ytile = nw & 31, xt = (nw >> 5) & 15, e = nw >> 9;
  int row_start = offsets[e], row_end = offsets[e + 1];
  int tile_row = row_start + ytile * 128;
  if (tile_row >= row_end) return;
  int n0 = xt * 128;

  __shared__ __align__(16) __bf16 As0[128][BK], As1[128][BK];

  int tid = threadIdx.x;
  int wid = tid >> 6, lane = tid & 63;
  int lrow = lane >> 2;
  int lke = (((lane & 3) ^ ((lane >> 3) & 3)) * 8);
  int lks = (((lane >> 4) ^ ((lane >> 1) & 3)) * 8);

  const __bf16* pa0 = abuf + (size_t)(tile_row + wid * 32 + lrow) * FE + lke;
  const __bf16* pa1 = pa0 + (size_t)16 * FE;

  int lr = lane & 15;
  int wm = (wid >> 1) * 64, wn = (wid & 1) * 64;
  int chunk = (lane >> 4) * 8;

  // blocked dwt: bn = 2*xt + (wid&1), kblocks = FE/32 = 32; frag ni at +ni*512.
  const __bf16* pB = dwt + (size_t)e * DIM * FE +
                     ((size_t)(2 * xt + (wid & 1)) * 32) * 2048 +
                     lr * 32 + chunk;

  f32x4 acc[4][4];
#pragma unroll
  for (int i = 0; i < 4; ++i)
#pragma unroll
    for (int j = 0; j < 4; ++j) acc[i][j] = (f32x4)0.f;

  bf16x8 af0, af1, af2, af3;
  bf16x8 eb0, eb1, eb2, eb3;
  bf16x8 ob0, ob1, ob2, ob3;

#define DN_STAGE_A(AS)                                       \
  do {                                                       \
    gll16(pa0, (void*)&AS[wid * 32][0]);                     \
    gll16(pa1, (void*)&AS[wid * 32 + 16][0]);                \
    pa0 += BK; pa1 += BK;                                    \
  } while (0)

#define DN_LOAD_B(B0, B1, B2, B3)                            \
  do {                                                       \
    B0 = *(const bf16x8*)pB;                                 \
    B1 = *(const bf16x8*)(pB + 512);                         \
    B2 = *(const bf16x8*)(pB + 1024);                        \
    B3 = *(const bf16x8*)(pB + 1536);                        \
    pB += 2048;                                              \
  } while (0)

#define DN_LOAD_A(AS)                                        \
  do {                                                       \
    af0 = *(const bf16x8*)&AS[wm + lr][lks];                 \
    af1 = *(const bf16x8*)&AS[wm + 16 + lr][lks];            \
    af2 = *(const bf16x8*)&AS[wm + 32 + lr][lks];            \
    af3 = *(const bf16x8*)&AS[wm + 48 + lr][lks];            \
  } while (0)

#define DN_MFMA(B0, B1, B2, B3)                              \
  do {                                                       \
    __builtin_amdgcn_s_setprio(1);                           \
    acc[0][0] = MFMA16(af0, B0, acc[0][0]);                  \
    acc[1][0] = MFMA16(af1, B0, acc[1][0]);                  \
    acc[2][0] = MFMA16(af2, B0, acc[2][0]);                  \
    acc[3][0] = MFMA16(af3, B0, acc[3][0]);                  \
    acc[0][1] = MFMA16(af0, B1, acc[0][1]);                  \
    acc[1][1] = MFMA16(af1, B1, acc[1][1]);                  \
    acc[2][1] = MFMA16(af2, B1, acc[2][1]);                  \
    acc[3][1] = MFMA16(af3, B1, acc[3][1]);                  \
    acc[0][2] = MFMA16(af0, B2, acc[0][2]);                  \
    acc[1][2] = MFMA16(af1, B2, acc[1][2]);                  \
    acc[2][2] = MFMA16(af2, B2, acc[2][2]);                  \
    acc[3][2] = MFMA16(af3, B2, acc[3][2]);                  \
    acc[0][3] = MFMA16(af0, B3, acc[0][3]);                  \
    acc[1][3] = MFMA16(af1, B3, acc[1][3]);                  \
    acc[2][3] = MFMA16(af2, B3, acc[2][3]);                  \
    acc[3][3] = MFMA16(af3, B3, acc[3][3]);                  \
    __builtin_amdgcn_s_setprio(0);                           \
  } while (0)

  // NT = 32. Prologue queue: [A0:2, B0:4, A1:2, B1:4]
  DN_STAGE_A(As0);
  DN_LOAD_B(eb0, eb1, eb2, eb3);
  DN_STAGE_A(As1);
  DN_LOAD_B(ob0, ob1, ob2, ob3);
#pragma unroll 1
  for (int it = 0; it < 15; ++it) {    // t = 0..29
    VMCNT6; BAR;
    DN_LOAD_A(As0);
    LGKM0; SCHED0; BAR;
    DN_STAGE_A(As0);
    DN_MFMA(eb0, eb1, eb2, eb3);
    DN_LOAD_B(eb0, eb1, eb2, eb3);
    VMCNT6; BAR;
    DN_LOAD_A(As1);
    LGKM0; SCHED0; BAR;
    DN_STAGE_A(As1);
    DN_MFMA(ob0, ob1, ob2, ob3);
    DN_LOAD_B(ob0, ob1, ob2, ob3);
  }
  VMCNT6; BAR;                          // t=30
  DN_LOAD_A(As0);
  LGKM0; SCHED0;
  DN_MFMA(eb0, eb1, eb2, eb3);
  VMCNT0; BAR;                          // t=31
  DN_LOAD_A(As1);
  LGKM0; SCHED0;
  DN_MFMA(ob0, ob1, ob2, ob3);
#undef DN_STAGE_A
#undef DN_LOAD_B
#undef DN_LOAD_A
#undef DN_MFMA

  int rowq = (lane >> 4) * 4;
#pragma unroll
  for (int mi = 0; mi < 4; ++mi) {
#pragma unroll
    for (int j = 0; j < 4; ++j) {
      int rg = tile_row + wm + mi * 16 + rowq + j;
      if (rg < row_end) {
#pragma unroll
        for (int ni = 0; ni < 4; ++ni) {
          dbuf[(size_t)rg * DIM + n0 + wn + ni * 16 + lr] = (__bf16)acc[mi][ni][j];
        }
      }
    }
  }
}

// ================= FALLBACK PATH (round-1 kernels, raw weights) ==============

#define PAD 8
__global__ __launch_bounds__(256) void k_gateup_fb(
    const __bf16* __restrict__ xbf, const float* __restrict__ gw,
    const float* __restrict__ uw, const int* __restrict__ row_token,
    const int* __restrict__ offsets, __bf16* __restrict__ abuf) {
  int e = blockIdx.z;
  int row_start = offsets[e], row_end = offsets[e + 1];
  int tile_row = row_start + blockIdx.y * 128;
  if (tile_row >= row_end) return;
  int n0 = blockIdx.x * 128;

  __shared__ __align__(16) __bf16 As[128][BK + PAD];
  __shared__ __align__(16) __bf16 Bgs[128][BK + PAD];
  __shared__ __align__(16) __bf16 Bus[128][BK + PAD];
  __shared__ int toks[128];

  int tid = threadIdx.x;
  if (tid < 128) {
    int r = tile_row + tid;
    toks[tid] = (r < row_end) ? row_token[r] : row_token[row_start];
  }
  __syncthreads();

  f32x4 accg[4][4]; f32x4 accu[4][4];
#pragma unroll
  for (int i = 0; i < 4; ++i)
#pragma unroll
    for (int j = 0; j < 4; ++j) { accg[i][j] = (f32x4)0.f; accu[i][j] = (f32x4)0.f; }

  int wid = tid >> 6, lane = tid & 63;
  int wm = (wid >> 1) * 64, wn = (wid & 1) * 64;
  int lr = lane & 15, lk = (lane >> 4) * 8;

  const float* gbase = gw + (size_t)e * DIM * FE + n0;
  const float* ubase = uw + (size_t)e * DIM * FE + n0;
  int n4 = (tid & 31) * 4;
  int kb = tid >> 5;

  for (int k0 = 0; k0 < DIM; k0 += BK) {
#pragma unroll
    for (int p = 0; p < 2; ++p) {
      int g = tid + p * 256;
      int r = g >> 2, kk = (g & 3) * 8;
      *(bf16x8*)&As[r][kk] = *(const bf16x8*)(xbf + (size_t)toks[r] * DIM + k0 + kk);
    }
#pragma unroll
    for (int p = 0; p < 4; ++p) {
      int k = kb + p * 8;
      const float4 vg = *(const float4*)(gbase + (size_t)(k0 + k) * FE + n4);
      const float4 vu = *(const float4*)(ubase + (size_t)(k0 + k) * FE + n4);
      Bgs[n4 + 0][k] = (__bf16)vg.x; Bgs[n4 + 1][k] = (__bf16)vg.y;
      Bgs[n4 + 2][k] = (__bf16)vg.z; Bgs[n4 + 3][k] = (__bf16)vg.w;
      Bus[n4 + 0][k] = (__bf16)vu.x; Bus[n4 + 1][k] = (__bf16)vu.y;
      Bus[n4 + 2][k] = (__bf16)vu.z; Bus[n4 + 3][k] = (__bf16)vu.w;
    }
    __syncthreads();

    bf16x8 af[4];
#pragma unroll
    for (int mi = 0; mi < 4; ++mi)
      af[mi] = *(const bf16x8*)&As[wm + mi * 16 + lr][lk];
#pragma unroll
    for (int ni = 0; ni < 4; ++ni) {
      bf16x8 bg = *(const bf16x8*)&Bgs[wn + ni * 16 + lr][lk];
      bf16x8 bu = *(const bf16x8*)&Bus[wn + ni * 16 + lr][lk];
#pragma unroll
      for (int mi = 0; mi < 4; ++mi) {
        accg[mi][ni] = MFMA16(af[mi], bg, accg[mi][ni]);
        accu[mi][ni] = MFMA16(af[mi], bu, accu[mi][ni]);
      }
    }
    __syncthreads();
  }

  int rowq = (lane >> 4) * 4;
#pragma unroll
  for (int mi = 0; mi < 4; ++mi) {
#pragma unroll
    for (int ni = 0; ni < 4; ++ni) {
#pragma unroll
      for (int j = 0; j < 4; ++j) {
        int rg = tile_row + wm + mi * 16 + rowq + j;
        if (rg < row_end) {
          float g = accg[mi][ni][j], u = accu[mi][ni][j];
          float sig = 1.f / (1.f + __expf(-g));
          abuf[(size_t)rg * FE + n0 + wn + ni * 16 + lr] = (__bf16)(g * sig * u);
        }
      }
    }
  }
}

__global__ __launch_bounds__(256) void k_down_fb(
    const __bf16* __restrict__ abuf, const float* __restrict__ dw,
    const int* __restrict__ row_token, const float* __restrict__ row_wt,
    const int* __restrict__ offsets, float* __restrict__ out) {
  int e = blockIdx.z;
  int row_start = offsets[e], row_end = offsets[e + 1];
  int tile_row = row_start + blockIdx.y * 128;
  if (tile_row >= row_end) return;
  int n0 = blockIdx.x * 128;

  __shared__ __align__(16) __bf16 As[128][BK + PAD];
  __shared__ __align__(16) __bf16 Bs[128][BK + PAD];

  int tid = threadIdx.x;
  f32x4 acc[4][4];
#pragma unroll
  for (int i = 0; i < 4; ++i)
#pragma unroll
    for (int j = 0; j < 4; ++j) acc[i][j] = (f32x4)0.f;

  int wid = tid >> 6, lane = tid & 63;
  int wm = (wid >> 1) * 64, wn = (wid & 1) * 64;
  int lr = lane & 15, lk = (lane >> 4) * 8;

  const float* dbase = dw + (size_t)e * FE * DIM + n0;
  int n4 = (tid & 31) * 4;
  int kb = tid >> 5;

  for (int k0 = 0; k0 < FE; k0 += BK) {
#pragma unroll
    for (int p = 0; p < 2; ++p) {
      int g = tid + p * 256;
      int r = g >> 2, kk = (g & 3) * 8;
      *(bf16x8*)&As[r][kk] = *(const bf16x8*)(abuf + (size_t)(tile_row + r) * FE + k0 + kk);
    }
#pragma unroll
    for (int p = 0; p < 4; ++p) {
      int k = kb + p * 8;
      const float4 vb = *(const float4*)(dbase + (size_t)(k0 + k) * DIM + n4);
      Bs[n4 + 0][k] = (__bf16)vb.x; Bs[n4 + 1][k] = (__bf16)vb.y;
      Bs[n4 + 2][k] = (__bf16)vb.z; Bs[n4 + 3][k] = (__bf16)vb.w;
    }
    __syncthreads();

    bf16x8 af[4];
#pragma unroll
    for (int mi = 0; mi < 4; ++mi)
      af[mi] = *(const bf16x8*)&As[wm + mi * 16 + lr][lk];
#pragma unroll
    for (int ni = 0; ni < 4; ++ni) {
      bf16x8 bb = *(const bf16x8*)&Bs[wn + ni * 16 + lr][lk];
#pragma unroll
      for (int mi = 0; mi < 4; ++mi)
        acc[mi][ni] = MFMA16(af[mi], bb, acc[mi][ni]);
    }
    __syncthreads();
  }

  int rowq = (lane >> 4) * 4;
#pragma unroll
  for (int mi = 0; mi < 4; ++mi) {
#pragma unroll
    for (int j = 0; j < 4; ++j) {
      int rg = tile_row + wm + mi * 16 + rowq + j;
      if (rg < row_end) {
        int tok = row_token[rg];
        float w = row_wt[rg];
#pragma unroll
        for (int ni = 0; ni < 4; ++ni) {
          atomicAdd(&out[(size_t)tok * DIM + n0 + wn + ni * 16 + lr],
                    acc[mi][ni][j] * w);
        }
      }
    }
  }
}

extern "C" void kernel_launch(void* const* d_in, const int* in_sizes, int n_in,
                              void* d_out, int out_size, void* d_ws, size_t ws_size,
                              hipStream_t stream) {
  const float* x  = (const float*)d_in[0];
  const float* rw = (const float*)d_in[1];
  const float* nw = (const float*)d_in[2];
  const float* gw = (const float*)d_in[3];
  const float* uw = (const float*)d_in[4];
  const float* dwp= (const float*)d_in[5];
  float* out = (float*)d_out;

  char* p = (char*)d_ws;
  int* offsets   = (int*)(p + 64);
  int* topi      = (int*)(p + 256);
  float* topw    = (float*)(p + 256 + 32768);
  int* row_token = (int*)(p + 256 + 65536);
  float* row_wt  = (float*)(p + 256 + 98304);
  int* invp      = (int*)(p + 256 + 131072);
  __bf16* xbf    = (__bf16*)(p + 256 + 163840);
  __bf16* abuf   = xbf + (size_t)TOK * DIM;
  __bf16* gwt    = abuf + ((size_t)2 * TOK + 128) * FE;
  __bf16* uwt    = gwt + (size_t)NE * DIM * FE;
  __bf16* dwt    = uwt + (size_t)NE * DIM * FE;
  __bf16* dbuf   = gwt;   // overlay: gwt/uwt dead after gateup

  size_t need = 256 + 163840 +
                ((size_t)TOK * DIM + ((size_t)2 * TOK + 128) * FE) * 2 +
                3 * (size_t)NE * DIM * FE * 2;
  bool fast = ws_size >= need;

  if (!fast)
    hipMemsetAsync(d_out, 0, (size_t)TOK * DIM * sizeof(float), stream);

  if (fast) {
    k_fused_cvt_router<<<TOK + 3072, 256, 0, stream>>>(
        x, rw, nw, xbf, topi, topw, gw, uw, dwp, gwt, uwt, dwt);
    k_prefix_place<<<1, 256, 0, stream>>>(offsets, topi, topw,
                                          row_token, row_wt, invp);
    k_gateup18<<<4096, 256, 0, stream>>>(xbf, gwt, uwt, row_token, offsets, abuf);
    k_down18<<<4096, 256, 0, stream>>>(abuf, dwt, offsets, dbuf);
    k_combine<<<TOK, 256, 0, stream>>>(dbuf, topw, invp, out);
  } else {
    k_fused_cvt_router<<<TOK, 256, 0, stream>>>(
        x, rw, nw, xbf, topi, topw, gw, uw, dwp, gwt, uwt, dwt);
    k_prefix_place<<<1, 256, 0, stream>>>(offsets, topi, topw,
                                          row_token, row_wt, invp);
    k_gateup_fb<<<dim3(FE / 128, 32, NE), 256, 0, stream>>>(xbf, gw, uw, row_token, offsets, abuf);
    k_down_fb<<<dim3(DIM / 128, 32, NE), 256, 0, stream>>>(abuf, dwp, row_token, row_wt, offsets, out);
  }
}

// Round 20
// 253.932 us; speedup vs baseline: 1.2332x; 1.2332x over previous
//
#include <hip/hip_runtime.h>
#include <hip/hip_bf16.h>

// Sparse MoE v20 == R17 exactly (verified best: 254us, passed).
// - fused router+convert kernel, NO cross-XCD global atomics (the R13-R16
//   ~160us serializer; removing them was -67us)
// - blocked bf16 weight layout ([64n][32k] 4KB blocks; streaming converts,
//   1KB-contiguous GEMM B fetches)
// - R8-schedule GEMMs: counted vmcnt(4), static 2-buffer LDS, bank swizzle
//   (conflicts==0), XCD-affine block remap (FETCH 147->74MB)
// - LDS-histogram prefix+place; dbuf+combine epilogue (no f32 atomics)
// T=4096 tokens, D=2048, E=8, F_E=1024, top-2, SCALE=4.

#define TOK 4096
#define DIM 2048
#define NE 8
#define FE 1024
#define SCALE_F 4.0f
#define BK 32

typedef __bf16 bf16x8 __attribute__((ext_vector_type(8)));
typedef __bf16 bf16x4 __attribute__((ext_vector_type(4)));
typedef float f32x4 __attribute__((ext_vector_type(4)));

__device__ __forceinline__ void gll16(const void* g, void* l) {
  __builtin_amdgcn_global_load_lds(
      (const __attribute__((address_space(1))) unsigned int*)g,
      (__attribute__((address_space(3))) unsigned int*)l, 16, 0, 0);
}

#define MFMA16(a, b, c) __builtin_amdgcn_mfma_f32_16x16x32_bf16((a), (b), (c), 0, 0, 0)
#define VMCNT4 asm volatile("s_waitcnt vmcnt(4)" ::: "memory")
#define VMCNT0 asm volatile("s_waitcnt vmcnt(0)" ::: "memory")
#define LGKM0  asm volatile("s_waitcnt lgkmcnt(0)" ::: "memory")
#define SCHED0 __builtin_amdgcn_sched_barrier(0)
#define BAR    __builtin_amdgcn_s_barrier()

// ---- fused: blocks [0,TOK) = router (NO global atomics); [TOK,+3072) = cvt --
__global__ __launch_bounds__(256) void k_fused_cvt_router(
    const float* __restrict__ x, const float* __restrict__ rw,
    const float* __restrict__ nwt, __bf16* __restrict__ xbf,
    int* __restrict__ topi, float* __restrict__ topw,
    const float* __restrict__ gw, const float* __restrict__ uw,
    const float* __restrict__ dwp, __bf16* __restrict__ gwt,
    __bf16* __restrict__ uwt, __bf16* __restrict__ dwt) {
  __shared__ __align__(16) __bf16 lt[128][136];   // 34 KB
  int tid = threadIdx.x;

  if (blockIdx.x < TOK) {
    int t = blockIdx.x;
    const float* xr = x + (size_t)t * DIM;
    float ssq = 0.f;
    float pe[NE];
#pragma unroll
    for (int e = 0; e < NE; ++e) pe[e] = 0.f;

#pragma unroll
    for (int i = 0; i < 2; ++i) {
      int c4 = tid + i * 256;
      float4 v = ((const float4*)xr)[c4];
      int c = c4 * 4;
      bf16x4 b;
      b[0] = (__bf16)v.x; b[1] = (__bf16)v.y; b[2] = (__bf16)v.z; b[3] = (__bf16)v.w;
      *(bf16x4*)(xbf + (size_t)t * DIM + c) = b;
      float m0 = nwt[c + 0] * v.x, m1 = nwt[c + 1] * v.y;
      float m2 = nwt[c + 2] * v.z, m3 = nwt[c + 3] * v.w;
      ssq += v.x * v.x + v.y * v.y + v.z * v.z + v.w * v.w;
#pragma unroll
      for (int e = 0; e < NE; ++e) {
        float4 rv = ((const float4*)(rw + (size_t)e * DIM))[c4];
        pe[e] += m0 * rv.x + m1 * rv.y + m2 * rv.z + m3 * rv.w;
      }
    }
#pragma unroll
    for (int off = 32; off > 0; off >>= 1) {
      ssq += __shfl_down(ssq, off);
#pragma unroll
      for (int e = 0; e < NE; ++e) pe[e] += __shfl_down(pe[e], off);
    }
    float (*red)[NE + 1] = (float (*)[NE + 1])&lt[0][0];
    int wid = tid >> 6, lane = tid & 63;
    if (lane == 0) {
      red[wid][0] = ssq;
#pragma unroll
      for (int e = 0; e < NE; ++e) red[wid][1 + e] = pe[e];
    }
    __syncthreads();
    if (tid == 0) {
      float s = red[0][0] + red[1][0] + red[2][0] + red[3][0];
      float rs = rsqrtf(s / (float)DIM + 1e-6f);
      float l[NE];
#pragma unroll
      for (int e = 0; e < NE; ++e)
        l[e] = (red[0][1 + e] + red[1][1 + e] + red[2][1 + e] + red[3][1 + e]) * rs;
      int i1 = 0;
#pragma unroll
      for (int e = 1; e < NE; ++e) if (l[e] > l[i1]) i1 = e;
      int i2 = -1;
#pragma unroll
      for (int e = 0; e < NE; ++e) if (e != i1 && (i2 < 0 || l[e] > l[i2])) i2 = e;
      float e2 = __expf(l[i2] - l[i1]);
      float inv = 1.f / (1.f + e2);
      topi[2 * t] = i1; topi[2 * t + 1] = i2;
      topw[2 * t] = inv; topw[2 * t + 1] = e2 * inv;
      // no global atomics here (histogram built in k_prefix_place)
    }
  } else {
    // ------------- convert path: [K][N] f32 -> blocked bf16 -------------
    int bx = blockIdx.x - TOK;           // 0..3071
    int m = bx >> 7;                     // matrix 0..23
    int tilex = bx & 127;
    int which = m >> 3, e = m & 7;
    const float* src; __bf16* dst; int K, N;
    if (which == 0)      { src = gw;  dst = gwt; K = DIM; N = FE; }
    else if (which == 1) { src = uw;  dst = uwt; K = DIM; N = FE; }
    else                 { src = dwp; dst = dwt; K = FE;  N = DIM; }
    src += (size_t)e * K * N;
    dst += (size_t)e * K * N;
    int tiles_n = N / 128;
    int k0 = (tilex / tiles_n) * 128, n0c = (tilex % tiles_n) * 128;

#pragma unroll
    for (int p = 0; p < 16; ++p) {
      int idx = tid + p * 256;
      int row = idx >> 5, c4 = idx & 31;
      float4 v = *(const float4*)(src + (size_t)(k0 + row) * N + n0c + c4 * 4);
      int cc = c4 * 4;
      lt[cc + 0][row] = (__bf16)v.x;
      lt[cc + 1][row] = (__bf16)v.y;
      lt[cc + 2][row] = (__bf16)v.z;
      lt[cc + 3][row] = (__bf16)v.w;
    }
    __syncthreads();
    int kblocks = K >> 5;
    int n_ = tid >> 2, kc = tid & 3;
#pragma unroll
    for (int q = 0; q < 8; ++q) {
      int bn = q >> 2, bk = q & 3;
      size_t blk = ((size_t)((n0c >> 6) + bn) * kblocks + (k0 >> 5) + bk) * 2048;
      bf16x8 w = *(const bf16x8*)&lt[bn * 64 + n_][bk * 32 + kc * 8];
      *(bf16x8*)(dst + blk + n_ * 32 + kc * 8) = w;
    }
  }
}

// ---- prefix + place with LDS histogram (replaces global counts atomics) ----
__global__ __launch_bounds__(256) void k_prefix_place(
    int* __restrict__ offsets, const int* __restrict__ topi,
    const float* __restrict__ topw, int* __restrict__ row_token,
    float* __restrict__ row_wt, int* __restrict__ invp) {
  __shared__ int hist[4][NE];
  __shared__ int lcur[NE];
  int tid = threadIdx.x, wid = tid >> 6;
  if (tid < 4 * NE) ((int*)hist)[tid] = 0;
  __syncthreads();
  for (int i = tid; i < 2 * TOK; i += 256)
    atomicAdd(&hist[wid][topi[i]], 1);
  __syncthreads();
  if (tid == 0) {
    int acc = 0;
    for (int e = 0; e < NE; ++e) {
      int c = hist[0][e] + hist[1][e] + hist[2][e] + hist[3][e];
      offsets[e] = acc;
      lcur[e] = acc;
      acc += c;
    }
    offsets[NE] = acc;
  }
  __syncthreads();
  for (int t = tid; t < TOK; t += 256) {
#pragma unroll
    for (int s = 0; s < 2; ++s) {
      int e = topi[2 * t + s];
      int pos = atomicAdd(&lcur[e], 1);
      row_token[pos] = t;
      row_wt[pos] = topw[2 * t + s] * SCALE_F;
      invp[2 * t + s] = pos;
    }
  }
}

// ---- combine: out[t] = SCALE*(w0*dbuf[p0] + w1*dbuf[p1]) --------------------
__global__ __launch_bounds__(256) void k_combine(
    const __bf16* __restrict__ dbuf, const float* __restrict__ topw,
    const int* __restrict__ invp, float* __restrict__ out) {
  int t = blockIdx.x;
  int c = threadIdx.x * 8;
  int p0 = invp[2 * t], p1 = invp[2 * t + 1];
  float w0 = topw[2 * t] * SCALE_F, w1 = topw[2 * t + 1] * SCALE_F;
  bf16x8 a = *(const bf16x8*)(dbuf + (size_t)p0 * DIM + c);
  bf16x8 b = *(const bf16x8*)(dbuf + (size_t)p1 * DIM + c);
  float4 o0, o1;
  o0.x = w0 * (float)a[0] + w1 * (float)b[0];
  o0.y = w0 * (float)a[1] + w1 * (float)b[1];
  o0.z = w0 * (float)a[2] + w1 * (float)b[2];
  o0.w = w0 * (float)a[3] + w1 * (float)b[3];
  o1.x = w0 * (float)a[4] + w1 * (float)b[4];
  o1.y = w0 * (float)a[5] + w1 * (float)b[5];
  o1.z = w0 * (float)a[6] + w1 * (float)b[6];
  o1.w = w0 * (float)a[7] + w1 * (float)b[7];
  *(float4*)(out + (size_t)t * DIM + c) = o0;
  *(float4*)(out + (size_t)t * DIM + c + 4) = o1;
}

// ================= FAST PATH (R8 GEMMs + XCD remap, blocked B) ===============
// XCD remap: nw=(lin&7)*512+(lin>>3); y=nw&31, x=(nw>>5)&15, e=nw>>9.
// Bank swizzle: stage src chunk ((lane&3)^((lane>>3)&3))*8,
// read chunk ((lane>>4)^((lane>>1)&3))*8.

__global__ __launch_bounds__(256) void k_gateup16(
    const __bf16* __restrict__ xbf, const __bf16* __restrict__ gwt,
    const __bf16* __restrict__ uwt, const int* __restrict__ row_token,
    const int* __restrict__ offsets, __bf16* __restrict__ abuf) {
  int lin = blockIdx.x;
  int nw = (lin & 7) * 512 + (lin >> 3);
  int ytile = nw & 31, xt = (nw >> 5) & 15, e = nw >> 9;
  int row_start = offsets[e], row_end = offsets[e + 1];
  int tile_row = row_start + ytile * 128;
  if (tile_row >= row_end) return;
  int n0 = xt * 64;

  __shared__ __align__(16) __bf16 As0[128][BK], As1[128][BK];
  __shared__ __align__(16) __bf16 Bg0[64][BK],  Bg1[64][BK];
  __shared__ __align__(16) __bf16 Bu0[64][BK],  Bu1[64][BK];
  __shared__ int toks[128];

  int tid = threadIdx.x;
  if (tid < 128) {
    int r = tile_row + tid;
    toks[tid] = (r < row_end) ? row_token[r] : row_token[row_start];
  }
  __syncthreads();

  int wid = tid >> 6, lane = tid & 63;
  int lrow = lane >> 2;
  int lke = (((lane & 3) ^ ((lane >> 3) & 3)) * 8);
  int lks = (((lane >> 4) ^ ((lane >> 1) & 3)) * 8);

  const __bf16* pa0 = xbf + (size_t)toks[wid * 32 + lrow] * DIM + lke;
  const __bf16* pa1 = xbf + (size_t)toks[wid * 32 + 16 + lrow] * DIM + lke;
  const __bf16* pg = gwt + (size_t)e * FE * DIM + (size_t)xt * 64 * 2048 +
                     (wid * 16 + lrow) * 32 + lke;
  const __bf16* pu = uwt + (size_t)e * FE * DIM + (size_t)xt * 64 * 2048 +
                     (wid * 16 + lrow) * 32 + lke;

  f32x4 accg[4][2], accu[4][2];
#pragma unroll
  for (int i = 0; i < 4; ++i)
#pragma unroll
    for (int j = 0; j < 2; ++j) { accg[i][j] = (f32x4)0.f; accu[i][j] = (f32x4)0.f; }

  int lr = lane & 15;
  int wm = (wid >> 1) * 64, wn = (wid & 1) * 32;

  bf16x8 af0, af1, af2, af3, bgv0, bgv1, buv0, buv1;

#define GU_STAGE(AS, BG, BU)                                 \
  do {                                                       \
    gll16(pa0, (void*)&AS[wid * 32][0]);                     \
    gll16(pa1, (void*)&AS[wid * 32 + 16][0]);                \
    gll16(pg, (void*)&BG[wid * 16][0]);                      \
    gll16(pu, (void*)&BU[wid * 16][0]);                      \
    pa0 += BK; pa1 += BK; pg += 2048; pu += 2048;            \
  } while (0)

#define GU_LOAD(AS, BG, BU)                                  \
  do {                                                       \
    af0 = *(const bf16x8*)&AS[wm + lr][lks];                 \
    af1 = *(const bf16x8*)&AS[wm + 16 + lr][lks];            \
    af2 = *(const bf16x8*)&AS[wm + 32 + lr][lks];            \
    af3 = *(const bf16x8*)&AS[wm + 48 + lr][lks];            \
    bgv0 = *(const bf16x8*)&BG[wn + lr][lks];                \
    bgv1 = *(const bf16x8*)&BG[wn + 16 + lr][lks];           \
    buv0 = *(const bf16x8*)&BU[wn + lr][lks];                \
    buv1 = *(const bf16x8*)&BU[wn + 16 + lr][lks];           \
  } while (0)

#define GU_MFMA()                                            \
  do {                                                       \
    __builtin_amdgcn_s_setprio(1);                           \
    accg[0][0] = MFMA16(af0, bgv0, accg[0][0]);              \
    accg[0][1] = MFMA16(af0, bgv1, accg[0][1]);              \
    accu[0][0] = MFMA16(af0, buv0, accu[0][0]);              \
    accu[0][1] = MFMA16(af0, buv1, accu[0][1]);              \
    accg[1][0] = MFMA16(af1, bgv0, accg[1][0]);              \
    accg[1][1] = MFMA16(af1, bgv1, accg[1][1]);              \
    accu[1][0] = MFMA16(af1, buv0, accu[1][0]);              \
    accu[1][1] = MFMA16(af1, buv1, accu[1][1]);              \
    accg[2][0] = MFMA16(af2, bgv0, accg[2][0]);              \
    accg[2][1] = MFMA16(af2, bgv1, accg[2][1]);              \
    accu[2][0] = MFMA16(af2, buv0, accu[2][0]);              \
    accu[2][1] = MFMA16(af2, buv1, accu[2][1]);              \
    accg[3][0] = MFMA16(af3, bgv0, accg[3][0]);              \
    accg[3][1] = MFMA16(af3, bgv1, accg[3][1]);              \
    accu[3][0] = MFMA16(af3, buv0, accu[3][0]);              \
    accu[3][1] = MFMA16(af3, buv1, accu[3][1]);              \
    __builtin_amdgcn_s_setprio(0);                           \
  } while (0)

  GU_STAGE(As0, Bg0, Bu0);
  GU_STAGE(As1, Bg1, Bu1);
#pragma unroll 1
  for (int it = 0; it < 31; ++it) {
    VMCNT4; BAR;
    GU_LOAD(As0, Bg0, Bu0);
    LGKM0; SCHED0; BAR;
    GU_STAGE(As0, Bg0, Bu0);
    GU_MFMA();
    VMCNT4; BAR;
    GU_LOAD(As1, Bg1, Bu1);
    LGKM0; SCHED0; BAR;
    GU_STAGE(As1, Bg1, Bu1);
    GU_MFMA();
  }
  VMCNT4; BAR;
  GU_LOAD(As0, Bg0, Bu0);
  GU_MFMA();
  VMCNT0; BAR;
  GU_LOAD(As1, Bg1, Bu1);
  GU_MFMA();
#undef GU_STAGE
#undef GU_LOAD
#undef GU_MFMA

  int rowq = (lane >> 4) * 4;
  f32x4* ag = &accg[0][0];
  f32x4* au = &accu[0][0];
#pragma unroll
  for (int mi = 0; mi < 4; ++mi) {
#pragma unroll
    for (int ni = 0; ni < 2; ++ni) {
#pragma unroll
      for (int j = 0; j < 4; ++j) {
        int rg = tile_row + wm + mi * 16 + rowq + j;
        if (rg < row_end) {
          float g = ag[mi * 2 + ni][j], u = au[mi * 2 + ni][j];
          float sig = 1.f / (1.f + __expf(-g));
          abuf[(size_t)rg * FE + n0 + wn + ni * 16 + lr] = (__bf16)(g * sig * u);
        }
      }
    }
  }
}

__global__ __launch_bounds__(256) void k_down16(
    const __bf16* __restrict__ abuf, const __bf16* __restrict__ dwt,
    const int* __restrict__ offsets, __bf16* __restrict__ dbuf) {
  int lin = blockIdx.x;
  int nw = (lin & 7) * 512 + (lin >> 3);
  int ytile = nw & 31, xt = (nw >> 5) & 15, e = nw >> 9;
  int row_start = offsets[e], row_end = offsets[e + 1];
  int tile_row = row_start + ytile * 128;
  if (tile_row >= row_end) return;
  int n0 = xt * 128;

  __shared__ __align__(16) __bf16 As0[128][BK], As1[128][BK];
  __shared__ __align__(16) __bf16 Bs0[128][BK], Bs1[128][BK];

  int tid = threadIdx.x;
  int wid = tid >> 6, lane = tid & 63;
  int lrow = lane >> 2;
  int lke = (((lane & 3) ^ ((lane >> 3) & 3)) * 8);
  int lks = (((lane >> 4) ^ ((lane >> 1) & 3)) * 8);

  const __bf16* pa0 = abuf + (size_t)(tile_row + wid * 32 + lrow) * FE + lke;
  const __bf16* pa1 = pa0 + (size_t)16 * FE;
  const __bf16* pb0 = dwt + (size_t)e * DIM * FE +
                      ((size_t)(2 * xt + (wid >> 1)) * 32) * 2048 +
                      ((wid & 1) * 32 + lrow) * 32 + lke;
  const __bf16* pb1 = pb0 + 16 * 32;

  f32x4 acc[4][4];
#pragma unroll
  for (int i = 0; i < 4; ++i)
#pragma unroll
    for (int j = 0; j < 4; ++j) acc[i][j] = (f32x4)0.f;

  int lr = lane & 15;
  int wm = (wid >> 1) * 64, wn = (wid & 1) * 64;

  bf16x8 af0, af1, af2, af3, bb0, bb1, bb2, bb3;

#define DN_STAGE(AS, BS)                                     \
  do {                                                       \
    gll16(pa0, (void*)&AS[wid * 32][0]);                     \
    gll16(pa1, (void*)&AS[wid * 32 + 16][0]);                \
    gll16(pb0, (void*)&BS[wid * 32][0]);                     \
    gll16(pb1, (void*)&BS[wid * 32 + 16][0]);                \
    pa0 += BK; pa1 += BK; pb0 += 2048; pb1 += 2048;          \
  } while (0)

#define DN_LOAD(AS, BS)                                      \
  do {                                                       \
    af0 = *(const bf16x8*)&AS[wm + lr][lks];                 \
    af1 = *(const bf16x8*)&AS[wm + 16 + lr][lks];            \
    af2 = *(const bf16x8*)&AS[wm + 32 + lr][lks];            \
    af3 = *(const bf16x8*)&AS[wm + 48 + lr][lks];            \
    bb0 = *(const bf16x8*)&BS[wn + lr][lks];                 \
    bb1 = *(const bf16x8*)&BS[wn + 16 + lr][lks];            \
    bb2 = *(const bf16x8*)&BS[wn + 32 + lr][lks];            \
    bb3 = *(const bf16x8*)&BS[wn + 48 + lr][lks];            \
  } while (0)

#define DN_MFMA()                                            \
  do {                                                       \
    __builtin_amdgcn_s_setprio(1);                           \
    acc[0][0] = MFMA16(af0, bb0, acc[0][0]);                 \
    acc[1][0] = MFMA16(af1, bb0, acc[1][0]);                 \
    acc[2][0] = MFMA16(af2, bb0, acc[2][0]);                 \
    acc[3][0] = MFMA16(af3, bb0, acc[3][0]);                 \
    acc[0][1] = MFMA16(af0, bb1, acc[0][1]);                 \
    acc[1][1] = MFMA16(af1, bb1, acc[1][1]);                 \
    acc[2][1] = MFMA16(af2, bb1, acc[2][1]);                 \
    acc[3][1] = MFMA16(af3, bb1, acc[3][1]);                 \
    acc[0][2] = MFMA16(af0, bb2, acc[0][2]);                 \
    acc[1][2] = MFMA16(af1, bb2, acc[1][2]);                 \
    acc[2][2] = MFMA16(af2, bb2, acc[2][2]);                 \
    acc[3][2] = MFMA16(af3, bb2, acc[3][2]);                 \
    acc[0][3] = MFMA16(af0, bb3, acc[0][3]);                 \
    acc[1][3] = MFMA16(af1, bb3, acc[1][3]);                 \
    acc[2][3] = MFMA16(af2, bb3, acc[2][3]);                 \
    acc[3][3] = MFMA16(af3, bb3, acc[3][3]);                 \
    __builtin_amdgcn_s_setprio(0);                           \
  } while (0)

  DN_STAGE(As0, Bs0);
  DN_STAGE(As1, Bs1);
#pragma unroll 1
  for (int it = 0; it < 15; ++it) {
    VMCNT4; BAR;
    DN_LOAD(As0, Bs0);
    LGKM0; SCHED0; BAR;
    DN_STAGE(As0, Bs0);
    DN_MFMA();
    VMCNT4; BAR;
    DN_LOAD(As1, Bs1);
    LGKM0; SCHED0; BAR;
    DN_STAGE(As1, Bs1);
    DN_MFMA();
  }
  VMCNT4; BAR;
  DN_LOAD(As0, Bs0);
  DN_MFMA();
  VMCNT0; BAR;
  DN_LOAD(As1, Bs1);
  DN_MFMA();
#undef DN_STAGE
#undef DN_LOAD
#undef DN_MFMA

  int rowq = (lane >> 4) * 4;
#pragma unroll
  for (int mi = 0; mi < 4; ++mi) {
#pragma unroll
    for (int j = 0; j < 4; ++j) {
      int rg = tile_row + wm + mi * 16 + rowq + j;
      if (rg < row_end) {
#pragma unroll
        for (int ni = 0; ni < 4; ++ni) {
          dbuf[(size_t)rg * DIM + n0 + wn + ni * 16 + lr] = (__bf16)acc[mi][ni][j];
        }
      }
    }
  }
}

// ================= FALLBACK PATH (round-1 kernels, raw weights) ==============

#define PAD 8
__global__ __launch_bounds__(256) void k_gateup_fb(
    const __bf16* __restrict__ xbf, const float* __restrict__ gw,
    const float* __restrict__ uw, const int* __restrict__ row_token,
    const int* __restrict__ offsets, __bf16* __restrict__ abuf) {
  int e = blockIdx.z;
  int row_start = offsets[e], row_end = offsets[e + 1];
  int tile_row = row_start + blockIdx.y * 128;
  if (tile_row >= row_end) return;
  int n0 = blockIdx.x * 128;

  __shared__ __align__(16) __bf16 As[128][BK + PAD];
  __shared__ __align__(16) __bf16 Bgs[128][BK + PAD];
  __shared__ __align__(16) __bf16 Bus[128][BK + PAD];
  __shared__ int toks[128];

  int tid = threadIdx.x;
  if (tid < 128) {
    int r = tile_row + tid;
    toks[tid] = (r < row_end) ? row_token[r] : row_token[row_start];
  }
  __syncthreads();

  f32x4 accg[4][4]; f32x4 accu[4][4];
#pragma unroll
  for (int i = 0; i < 4; ++i)
#pragma unroll
    for (int j = 0; j < 4; ++j) { accg[i][j] = (f32x4)0.f; accu[i][j] = (f32x4)0.f; }

  int wid = tid >> 6, lane = tid & 63;
  int wm = (wid >> 1) * 64, wn = (wid & 1) * 64;
  int lr = lane & 15, lk = (lane >> 4) * 8;

  const float* gbase = gw + (size_t)e * DIM * FE + n0;
  const float* ubase = uw + (size_t)e * DIM * FE + n0;
  int n4 = (tid & 31) * 4;
  int kb = tid >> 5;

  for (int k0 = 0; k0 < DIM; k0 += BK) {
#pragma unroll
    for (int p = 0; p < 2; ++p) {
      int g = tid + p * 256;
      int r = g >> 2, kk = (g & 3) * 8;
      *(bf16x8*)&As[r][kk] = *(const bf16x8*)(xbf + (size_t)toks[r] * DIM + k0 + kk);
    }
#pragma unroll
    for (int p = 0; p < 4; ++p) {
      int k = kb + p * 8;
      const float4 vg = *(const float4*)(gbase + (size_t)(k0 + k) * FE + n4);
      const float4 vu = *(const float4*)(ubase + (size_t)(k0 + k) * FE + n4);
      Bgs[n4 + 0][k] = (__bf16)vg.x; Bgs[n4 + 1][k] = (__bf16)vg.y;
      Bgs[n4 + 2][k] = (__bf16)vg.z; Bgs[n4 + 3][k] = (__bf16)vg.w;
      Bus[n4 + 0][k] = (__bf16)vu.x; Bus[n4 + 1][k] = (__bf16)vu.y;
      Bus[n4 + 2][k] = (__bf16)vu.z; Bus[n4 + 3][k] = (__bf16)vu.w;
    }
    __syncthreads();

    bf16x8 af[4];
#pragma unroll
    for (int mi = 0; mi < 4; ++mi)
      af[mi] = *(const bf16x8*)&As[wm + mi * 16 + lr][lk];
#pragma unroll
    for (int ni = 0; ni < 4; ++ni) {
      bf16x8 bg = *(const bf16x8*)&Bgs[wn + ni * 16 + lr][lk];
      bf16x8 bu = *(const bf16x8*)&Bus[wn + ni * 16 + lr][lk];
#pragma unroll
      for (int mi = 0; mi < 4; ++mi) {
        accg[mi][ni] = MFMA16(af[mi], bg, accg[mi][ni]);
        accu[mi][ni] = MFMA16(af[mi], bu, accu[mi][ni]);
      }
    }
    __syncthreads();
  }

  int rowq = (lane >> 4) * 4;
#pragma unroll
  for (int mi = 0; mi < 4; ++mi) {
#pragma unroll
    for (int ni = 0; ni < 4; ++ni) {
#pragma unroll
      for (int j = 0; j < 4; ++j) {
        int rg = tile_row + wm + mi * 16 + rowq + j;
        if (rg < row_end) {
          float g = accg[mi][ni][j], u = accu[mi][ni][j];
          float sig = 1.f / (1.f + __expf(-g));
          abuf[(size_t)rg * FE + n0 + wn + ni * 16 + lr] = (__bf16)(g * sig * u);
        }
      }
    }
  }
}

__global__ __launch_bounds__(256) void k_down_fb(
    const __bf16* __restrict__ abuf, const float* __restrict__ dw,
    const int* __restrict__ row_token, const float* __restrict__ row_wt,
    const int* __restrict__ offsets, float* __restrict__ out) {
  int e = blockIdx.z;
  int row_start = offsets[e], row_end = offsets[e + 1];
  int tile_row = row_start + blockIdx.y * 128;
  if (tile_row >= row_end) return;
  int n0 = blockIdx.x * 128;

  __shared__ __align__(16) __bf16 As[128][BK + PAD];
  __shared__ __align__(16) __bf16 Bs[128][BK + PAD];

  int tid = threadIdx.x;
  f32x4 acc[4][4];
#pragma unroll
  for (int i = 0; i < 4; ++i)
#pragma unroll
    for (int j = 0; j < 4; ++j) acc[i][j] = (f32x4)0.f;

  int wid = tid >> 6, lane = tid & 63;
  int wm = (wid >> 1) * 64, wn = (wid & 1) * 64;
  int lr = lane & 15, lk = (lane >> 4) * 8;

  const float* dbase = dw + (size_t)e * FE * DIM + n0;
  int n4 = (tid & 31) * 4;
  int kb = tid >> 5;

  for (int k0 = 0; k0 < FE; k0 += BK) {
#pragma unroll
    for (int p = 0; p < 2; ++p) {
      int g = tid + p * 256;
      int r = g >> 2, kk = (g & 3) * 8;
      *(bf16x8*)&As[r][kk] = *(const bf16x8*)(abuf + (size_t)(tile_row + r) * FE + k0 + kk);
    }
#pragma unroll
    for (int p = 0; p < 4; ++p) {
      int k = kb + p * 8;
      const float4 vb = *(const float4*)(dbase + (size_t)(k0 + k) * DIM + n4);
      Bs[n4 + 0][k] = (__bf16)vb.x; Bs[n4 + 1][k] = (__bf16)vb.y;
      Bs[n4 + 2][k] = (__bf16)vb.z; Bs[n4 + 3][k] = (__bf16)vb.w;
    }
    __syncthreads();

    bf16x8 af[4];
#pragma unroll
    for (int mi = 0; mi < 4; ++mi)
      af[mi] = *(const bf16x8*)&As[wm + mi * 16 + lr][lk];
#pragma unroll
    for (int ni = 0; ni < 4; ++ni) {
      bf16x8 bb = *(const bf16x8*)&Bs[wn + ni * 16 + lr][lk];
#pragma unroll
      for (int mi = 0; mi < 4; ++mi)
        acc[mi][ni] = MFMA16(af[mi], bb, acc[mi][ni]);
    }
    __syncthreads();
  }

  int rowq = (lane >> 4) * 4;
#pragma unroll
  for (int mi = 0; mi < 4; ++mi) {
#pragma unroll
    for (int j = 0; j < 4; ++j) {
      int rg = tile_row + wm + mi * 16 + rowq + j;
      if (rg < row_end) {
        int tok = row_token[rg];
        float w = row_wt[rg];
#pragma unroll
        for (int ni = 0; ni < 4; ++ni) {
          atomicAdd(&out[(size_t)tok * DIM + n0 + wn + ni * 16 + lr],
                    acc[mi][ni][j] * w);
        }
      }
    }
  }
}

extern "C" void kernel_launch(void* const* d_in, const int* in_sizes, int n_in,
                              void* d_out, int out_size, void* d_ws, size_t ws_size,
                              hipStream_t stream) {
  const float* x  = (const float*)d_in[0];
  const float* rw = (const float*)d_in[1];
  const float* nw = (const float*)d_in[2];
  const float* gw = (const float*)d_in[3];
  const float* uw = (const float*)d_in[4];
  const float* dwp= (const float*)d_in[5];
  float* out = (float*)d_out;

  char* p = (char*)d_ws;
  int* offsets   = (int*)(p + 64);
  int* topi      = (int*)(p + 256);
  float* topw    = (float*)(p + 256 + 32768);
  int* row_token = (int*)(p + 256 + 65536);
  float* row_wt  = (float*)(p + 256 + 98304);
  int* invp      = (int*)(p + 256 + 131072);
  __bf16* xbf    = (__bf16*)(p + 256 + 163840);
  __bf16* abuf   = xbf + (size_t)TOK * DIM;
  __bf16* gwt    = abuf + ((size_t)2 * TOK + 128) * FE;
  __bf16* uwt    = gwt + (size_t)NE * DIM * FE;
  __bf16* dwt    = uwt + (size_t)NE * DIM * FE;
  __bf16* dbuf   = gwt;   // overlay: gwt/uwt dead after gateup

  size_t need = 256 + 163840 +
                ((size_t)TOK * DIM + ((size_t)2 * TOK + 128) * FE) * 2 +
                3 * (size_t)NE * DIM * FE * 2;
  bool fast = ws_size >= need;

  if (!fast)
    hipMemsetAsync(d_out, 0, (size_t)TOK * DIM * sizeof(float), stream);

  if (fast) {
    k_fused_cvt_router<<<TOK + 3072, 256, 0, stream>>>(
        x, rw, nw, xbf, topi, topw, gw, uw, dwp, gwt, uwt, dwt);
    k_prefix_place<<<1, 256, 0, stream>>>(offsets, topi, topw,
                                          row_token, row_wt, invp);
    k_gateup16<<<4096, 256, 0, stream>>>(xbf, gwt, uwt, row_token, offsets, abuf);
    k_down16<<<4096, 256, 0, stream>>>(abuf, dwt, offsets, dbuf);
    k_combine<<<TOK, 256, 0, stream>>>(dbuf, topw, invp, out);
  } else {
    k_fused_cvt_router<<<TOK, 256, 0, stream>>>(
        x, rw, nw, xbf, topi, topw, gw, uw, dwp, gwt, uwt, dwt);
    k_prefix_place<<<1, 256, 0, stream>>>(offsets, topi, topw,
                                          row_token, row_wt, invp);
    k_gateup_fb<<<dim3(FE / 128, 32, NE), 256, 0, stream>>>(xbf, gw, uw, row_token, offsets, abuf);
    k_down_fb<<<dim3(DIM / 128, 32, NE), 256, 0, stream>>>(abuf, dwp, row_token, row_wt, offsets, out);
  }
}